// Round 5
// baseline (25.431 us; speedup 1.0000x reference)
//
#include <hip/hip_runtime.h>
#include <math.h>

#define NLUT 256    // intervals; nodes = NLUT+1. LDS paired table = 2 KB.

typedef float f32x4 __attribute__((ext_vector_type(4)));

// Fast tanh via hardware exp: tanh(x) = (e^2x - 1)/(e^2x + 1). ~1e-7 rel err.
__device__ __forceinline__ float fast_tanh(float x) {
    float e = __expf(2.0f * x);
    return __fdividef(e - 1.0f, e + 1.0f);
}

// ---------------------------------------------------------------------------
// Full QCNN evaluation for one scalar input x (the broadcast conv_val).
// Layers: 8->16->16->12->8->4->4->1. Weight pointers point into LDS.
// Bitwise identical to all previous rounds.
// ---------------------------------------------------------------------------
__device__ __forceinline__ float eval_net(
    float x,
    const float* W_fm, const float* b_fm,
    const float* W_c1, const float* b_c1,
    const float* W_p1, const float* b_p1,
    const float* W_c2, const float* b_c2,
    const float* W_p2, const float* b_p2,
    const float* W_c3, const float* b_c3,
    const float* W_h,  const float* b_h)
{
    float h[16], g[16];
    #pragma unroll
    for (int j = 0; j < 16; ++j) {
        float a = b_fm[j];
        #pragma unroll
        for (int i = 0; i < 8; ++i) a = fmaf(x, W_fm[i * 16 + j], a);
        h[j] = fast_tanh(a);
    }
    #pragma unroll
    for (int j = 0; j < 16; ++j) {
        float a = b_c1[j];
        #pragma unroll
        for (int i = 0; i < 16; ++i) a = fmaf(h[i], W_c1[i * 16 + j], a);
        g[j] = fast_tanh(a);
    }
    #pragma unroll
    for (int j = 0; j < 12; ++j) {
        float a = b_p1[j];
        #pragma unroll
        for (int i = 0; i < 16; ++i) a = fmaf(g[i], W_p1[i * 12 + j], a);
        h[j] = fast_tanh(a);
    }
    #pragma unroll
    for (int j = 0; j < 8; ++j) {
        float a = b_c2[j];
        #pragma unroll
        for (int i = 0; i < 12; ++i) a = fmaf(h[i], W_c2[i * 8 + j], a);
        g[j] = fast_tanh(a);
    }
    #pragma unroll
    for (int j = 0; j < 4; ++j) {
        float a = b_p2[j];
        #pragma unroll
        for (int i = 0; i < 8; ++i) a = fmaf(g[i], W_p2[i * 4 + j], a);
        h[j] = fast_tanh(a);
    }
    #pragma unroll
    for (int j = 0; j < 4; ++j) {
        float a = b_c3[j];
        #pragma unroll
        for (int i = 0; i < 4; ++i) a = fmaf(h[i], W_c3[i * 4 + j], a);
        g[j] = fast_tanh(a);
    }
    float a = b_h[0];
    #pragma unroll
    for (int i = 0; i < 4; ++i) a = fmaf(g[i], W_h[i], a);
    return __fdividef(1.0f, 1.0f + __expf(-a));
}

// ---------------------------------------------------------------------------
// FUSED kernel, persistent: 256 blocks x 1024 threads = 1 block/CU.
// Phase 1: build the 257-node LUT in LDS (one eval deep, per block).
// Phase 2: streaming with FULL cache-bypass flags (sc0 sc1 nt) via inline
//   asm. Round-4's __builtin_nontemporal (nt bit only) cut 28.4 -> 24.9 us,
//   consistent with eliminating store-side L2/L3 allocate+evict only. The
//   read side still allocates Infinity-Cache lines, each evicting a dirty
//   poison line from the harness's 256 MiB fill (~67 MB hidden writeback).
//   sc0 sc1 = system scope (bypass L1/L2), nt = no-reuse: the strongest
//   "stream, don't allocate" policy the gfx950 ISA encodes.
//   Loads + s_waitcnt issued in ONE asm block (no hoisting hazard:
//   consumers data-depend on the asm outputs, waitcnt precedes them).
// Math bitwise identical to prior rounds (same bits loaded/stored).
// ---------------------------------------------------------------------------
__global__ __launch_bounds__(1024) void qcnn_fused_kernel(
    const f32x4* __restrict__ data,
    const float* __restrict__ conv_w, const float* __restrict__ conv_b,
    const float* __restrict__ W_fm, const float* __restrict__ b_fm,
    const float* __restrict__ W_c1, const float* __restrict__ b_c1,
    const float* __restrict__ W_p1, const float* __restrict__ b_p1,
    const float* __restrict__ W_c2, const float* __restrict__ b_c2,
    const float* __restrict__ W_p2, const float* __restrict__ b_p2,
    const float* __restrict__ W_c3, const float* __restrict__ b_c3,
    const float* __restrict__ W_h,  const float* __restrict__ b_h,
    float* __restrict__ out, int n)
{
    __shared__ float  s[785];
    __shared__ float  sv[NLUT + 1];
    __shared__ float2 lutl[NLUT];

    const int t = threadIdx.x;

    // ---- Phase 1a: stage weights into LDS ----
    if (t < 128)  s[t]       = W_fm[t];
    if (t < 16)   s[128 + t] = b_fm[t];
    if (t < 256)  s[144 + t] = W_c1[t];
    if (t < 16)   s[400 + t] = b_c1[t];
    if (t < 192)  s[416 + t] = W_p1[t];
    if (t < 12)   s[608 + t] = b_p1[t];
    if (t < 96)   s[620 + t] = W_c2[t];
    if (t < 8)    s[716 + t] = b_c2[t];
    if (t < 32)   s[724 + t] = W_p2[t];
    if (t < 4)    s[756 + t] = b_p2[t];
    if (t < 16)   s[760 + t] = W_c3[t];
    if (t < 4)    s[776 + t] = b_c3[t];
    if (t < 4)    s[780 + t] = W_h[t];
    if (t == 0)   s[784]     = b_h[0];
    __syncthreads();

    // ---- Phase 1b: 257 parallel node evals (one eval deep) ----
    if (t <= NLUT) {
        sv[t] = eval_net((float)t * (1.0f / (float)NLUT),
                         s + 0,   s + 128, s + 144, s + 400, s + 416, s + 608,
                         s + 620, s + 716, s + 724, s + 756, s + 760, s + 776,
                         s + 780, s + 784);
    }
    __syncthreads();
    if (t < NLUT) lutl[t] = make_float2(sv[t], sv[t + 1]);
    __syncthreads();

    // ---- Phase 2: streaming with sc0 sc1 nt (no cache allocation) ----
    const float w0 = conv_w[0], w1 = conv_w[1], w2 = conv_w[2], w3 = conv_w[3];
    const float cb = conv_b[0];

    const int tid = blockIdx.x * 1024 + t;
    const int stride = gridDim.x * 1024;

    int i = tid;
    for (; i + 3 * stride < n; i += 4 * stride) {
        const f32x4* p0 = data + i;
        const f32x4* p1 = data + i + stride;
        const f32x4* p2 = data + i + 2 * stride;
        const f32x4* p3 = data + i + 3 * stride;
        f32x4 d0, d1, d2, d3;
        asm volatile(
            "global_load_dwordx4 %0, %4, off sc0 sc1 nt\n\t"
            "global_load_dwordx4 %1, %5, off sc0 sc1 nt\n\t"
            "global_load_dwordx4 %2, %6, off sc0 sc1 nt\n\t"
            "global_load_dwordx4 %3, %7, off sc0 sc1 nt\n\t"
            "s_waitcnt vmcnt(0)"
            : "=&v"(d0), "=&v"(d1), "=&v"(d2), "=&v"(d3)
            : "v"(p0), "v"(p1), "v"(p2), "v"(p3)
            : "memory");

        float r[4];
        f32x4 dd[4] = {d0, d1, d2, d3};
        #pragma unroll
        for (int k = 0; k < 4; ++k) {
            float logit = fmaf(dd[k].x, w0, fmaf(dd[k].y, w1,
                          fmaf(dd[k].z, w2, fmaf(dd[k].w, w3, cb))));
            float cv = __fdividef(1.0f, 1.0f + __expf(-logit));
            float tt = cv * (float)NLUT;          // in [0, NLUT]
            int idx = (int)tt;
            idx = idx < NLUT ? idx : (NLUT - 1);
            idx = idx > 0 ? idx : 0;
            float fr = tt - (float)idx;
            float2 v = lutl[idx];                 // LDS ds_read_b64
            r[k] = fmaf(fr, v.y - v.x, v.x);
        }

        asm volatile(
            "global_store_dword %0, %4, off sc0 sc1 nt\n\t"
            "global_store_dword %1, %5, off sc0 sc1 nt\n\t"
            "global_store_dword %2, %6, off sc0 sc1 nt\n\t"
            "global_store_dword %3, %7, off sc0 sc1 nt"
            :
            : "v"(out + i), "v"(out + i + stride),
              "v"(out + i + 2 * stride), "v"(out + i + 3 * stride),
              "v"(r[0]), "v"(r[1]), "v"(r[2]), "v"(r[3])
            : "memory");
    }
    // Tail (empty for B = 4M with this grid, kept for robustness).
    for (; i < n; i += stride) {
        f32x4 d = __builtin_nontemporal_load(data + i);
        float logit = fmaf(d.x, w0, fmaf(d.y, w1,
                      fmaf(d.z, w2, fmaf(d.w, w3, cb))));
        float cv = __fdividef(1.0f, 1.0f + __expf(-logit));
        float tt = cv * (float)NLUT;
        int idx = (int)tt;
        idx = idx < NLUT ? idx : (NLUT - 1);
        idx = idx > 0 ? idx : 0;
        float fr = tt - (float)idx;
        float2 v = lutl[idx];
        __builtin_nontemporal_store(fmaf(fr, v.y - v.x, v.x), out + i);
    }
}

extern "C" void kernel_launch(void* const* d_in, const int* in_sizes, int n_in,
                              void* d_out, int out_size, void* d_ws, size_t ws_size,
                              hipStream_t stream) {
    const float* data   = (const float*)d_in[0];
    const float* conv_w = (const float*)d_in[1];
    const float* conv_b = (const float*)d_in[2];
    const float* W_fm = (const float*)d_in[3];  const float* b_fm = (const float*)d_in[4];
    const float* W_c1 = (const float*)d_in[5];  const float* b_c1 = (const float*)d_in[6];
    const float* W_p1 = (const float*)d_in[7];  const float* b_p1 = (const float*)d_in[8];
    const float* W_c2 = (const float*)d_in[9];  const float* b_c2 = (const float*)d_in[10];
    const float* W_p2 = (const float*)d_in[11]; const float* b_p2 = (const float*)d_in[12];
    const float* W_c3 = (const float*)d_in[13]; const float* b_c3 = (const float*)d_in[14];
    const float* W_h  = (const float*)d_in[15]; const float* b_h  = (const float*)d_in[16];
    float* out = (float*)d_out;
    const int B = in_sizes[0] / 4;  // samples; data is B x (1,2,2) = B float4s

    // 256 blocks x 1024 threads: one persistent block per CU, 16 waves/CU.
    qcnn_fused_kernel<<<256, 1024, 0, stream>>>(
        (const f32x4*)data, conv_w, conv_b,
        W_fm, b_fm, W_c1, b_c1, W_p1, b_p1, W_c2, b_c2,
        W_p2, b_p2, W_c3, b_c3, W_h, b_h, out, B);
}

// Round 6
// 24.879 us; speedup vs baseline: 1.0222x; 1.0222x over previous
//
#include <hip/hip_runtime.h>
#include <math.h>

#define NLUT 256    // intervals; nodes = NLUT+1. LDS paired table = 2 KB.

typedef float f32x4 __attribute__((ext_vector_type(4)));

// Fast tanh via hardware exp: tanh(x) = (e^2x - 1)/(e^2x + 1). ~1e-7 rel err.
__device__ __forceinline__ float fast_tanh(float x) {
    float e = __expf(2.0f * x);
    return __fdividef(e - 1.0f, e + 1.0f);
}

// ---------------------------------------------------------------------------
// Full QCNN evaluation for one scalar input x (the broadcast conv_val).
// Layers: 8->16->16->12->8->4->4->1. Weight pointers point into LDS.
// Bitwise identical to all previous rounds.
// ---------------------------------------------------------------------------
__device__ __forceinline__ float eval_net(
    float x,
    const float* W_fm, const float* b_fm,
    const float* W_c1, const float* b_c1,
    const float* W_p1, const float* b_p1,
    const float* W_c2, const float* b_c2,
    const float* W_p2, const float* b_p2,
    const float* W_c3, const float* b_c3,
    const float* W_h,  const float* b_h)
{
    float h[16], g[16];
    #pragma unroll
    for (int j = 0; j < 16; ++j) {
        float a = b_fm[j];
        #pragma unroll
        for (int i = 0; i < 8; ++i) a = fmaf(x, W_fm[i * 16 + j], a);
        h[j] = fast_tanh(a);
    }
    #pragma unroll
    for (int j = 0; j < 16; ++j) {
        float a = b_c1[j];
        #pragma unroll
        for (int i = 0; i < 16; ++i) a = fmaf(h[i], W_c1[i * 16 + j], a);
        g[j] = fast_tanh(a);
    }
    #pragma unroll
    for (int j = 0; j < 12; ++j) {
        float a = b_p1[j];
        #pragma unroll
        for (int i = 0; i < 16; ++i) a = fmaf(g[i], W_p1[i * 12 + j], a);
        h[j] = fast_tanh(a);
    }
    #pragma unroll
    for (int j = 0; j < 8; ++j) {
        float a = b_c2[j];
        #pragma unroll
        for (int i = 0; i < 12; ++i) a = fmaf(h[i], W_c2[i * 8 + j], a);
        g[j] = fast_tanh(a);
    }
    #pragma unroll
    for (int j = 0; j < 4; ++j) {
        float a = b_p2[j];
        #pragma unroll
        for (int i = 0; i < 8; ++i) a = fmaf(g[i], W_p2[i * 4 + j], a);
        h[j] = fast_tanh(a);
    }
    #pragma unroll
    for (int j = 0; j < 4; ++j) {
        float a = b_c3[j];
        #pragma unroll
        for (int i = 0; i < 4; ++i) a = fmaf(h[i], W_c3[i * 4 + j], a);
        g[j] = fast_tanh(a);
    }
    float a = b_h[0];
    #pragma unroll
    for (int i = 0; i < 4; ++i) a = fmaf(g[i], W_h[i], a);
    return __fdividef(1.0f, 1.0f + __expf(-a));
}

// Conv + sigmoid + LUT-index prep: everything that does NOT need the LUT.
__device__ __forceinline__ void prep_sample(
    f32x4 d, float w0, float w1, float w2, float w3, float cb,
    int* idx_out, float* fr_out)
{
    float logit = fmaf(d.x, w0, fmaf(d.y, w1,
                  fmaf(d.z, w2, fmaf(d.w, w3, cb))));
    float cv = __fdividef(1.0f, 1.0f + __expf(-logit));
    float tt = cv * (float)NLUT;          // in [0, NLUT]
    int idx = (int)tt;
    idx = idx < NLUT ? idx : (NLUT - 1);
    idx = idx > 0 ? idx : 0;
    *idx_out = idx;
    *fr_out = tt - (float)idx;
}

// ---------------------------------------------------------------------------
// FUSED kernel, persistent: 256 blocks x 1024 threads = 1 block/CU.
//  - Round-4 builtin nt loads/stores (best measured: 24.9 us; the round-5
//    sc0/sc1/nt asm variant was +0.5 us scheduling loss, reverted).
//  - NEW: first grid-stride batch is PEELED ahead of the LUT build. The
//    first 4 nt-loads + conv/sigmoid/index math are LUT-independent, so
//    they issue before the eval/barrier; the ~1.3 us LUT-build latency
//    hides under the first batch's HBM misses instead of preceding them.
//  - Remaining cost model (rounds 3-5): mandatory 84 MB + ~67 MB dirty-
//    poison writeback from read-side Infinity-Cache allocation (memory-
//    side cache; request flags can't suppress it) ~= 151 MB at ~6.5 TB/s.
// Math bitwise identical to all prior rounds.
// ---------------------------------------------------------------------------
__global__ __launch_bounds__(1024) void qcnn_fused_kernel(
    const f32x4* __restrict__ data,
    const float* __restrict__ conv_w, const float* __restrict__ conv_b,
    const float* __restrict__ W_fm, const float* __restrict__ b_fm,
    const float* __restrict__ W_c1, const float* __restrict__ b_c1,
    const float* __restrict__ W_p1, const float* __restrict__ b_p1,
    const float* __restrict__ W_c2, const float* __restrict__ b_c2,
    const float* __restrict__ W_p2, const float* __restrict__ b_p2,
    const float* __restrict__ W_c3, const float* __restrict__ b_c3,
    const float* __restrict__ W_h,  const float* __restrict__ b_h,
    float* __restrict__ out, int n)
{
    __shared__ float  s[785];
    __shared__ float  sv[NLUT + 1];
    __shared__ float2 lutl[NLUT];

    const int t = threadIdx.x;

    // ---- Phase 1a: stage weights into LDS ----
    if (t < 128)  s[t]       = W_fm[t];
    if (t < 16)   s[128 + t] = b_fm[t];
    if (t < 256)  s[144 + t] = W_c1[t];
    if (t < 16)   s[400 + t] = b_c1[t];
    if (t < 192)  s[416 + t] = W_p1[t];
    if (t < 12)   s[608 + t] = b_p1[t];
    if (t < 96)   s[620 + t] = W_c2[t];
    if (t < 8)    s[716 + t] = b_c2[t];
    if (t < 32)   s[724 + t] = W_p2[t];
    if (t < 4)    s[756 + t] = b_p2[t];
    if (t < 16)   s[760 + t] = W_c3[t];
    if (t < 4)    s[776 + t] = b_c3[t];
    if (t < 4)    s[780 + t] = W_h[t];
    if (t == 0)   s[784]     = b_h[0];
    __syncthreads();

    const float w0 = conv_w[0], w1 = conv_w[1], w2 = conv_w[2], w3 = conv_w[3];
    const float cb = conv_b[0];

    const int tid = blockIdx.x * 1024 + t;
    const int stride = gridDim.x * 1024;

    // ---- Peel: issue first-batch loads + LUT-independent math NOW ----
    const bool full0 = (tid + 3 * stride < n);
    int   pidx[4];
    float pfr[4];
    if (full0) {
        f32x4 d0 = __builtin_nontemporal_load(data + tid);
        f32x4 d1 = __builtin_nontemporal_load(data + tid + stride);
        f32x4 d2 = __builtin_nontemporal_load(data + tid + 2 * stride);
        f32x4 d3 = __builtin_nontemporal_load(data + tid + 3 * stride);
        prep_sample(d0, w0, w1, w2, w3, cb, &pidx[0], &pfr[0]);
        prep_sample(d1, w0, w1, w2, w3, cb, &pidx[1], &pfr[1]);
        prep_sample(d2, w0, w1, w2, w3, cb, &pidx[2], &pfr[2]);
        prep_sample(d3, w0, w1, w2, w3, cb, &pidx[3], &pfr[3]);
    }

    // ---- Phase 1b: LUT build (overlaps the peel's HBM misses) ----
    if (t <= NLUT) {
        sv[t] = eval_net((float)t * (1.0f / (float)NLUT),
                         s + 0,   s + 128, s + 144, s + 400, s + 416, s + 608,
                         s + 620, s + 716, s + 724, s + 756, s + 760, s + 776,
                         s + 780, s + 784);
    }
    __syncthreads();
    if (t < NLUT) lutl[t] = make_float2(sv[t], sv[t + 1]);
    __syncthreads();

    int i = tid;
    // ---- Finish peeled batch ----
    if (full0) {
        #pragma unroll
        for (int k = 0; k < 4; ++k) {
            float2 v = lutl[pidx[k]];
            __builtin_nontemporal_store(fmaf(pfr[k], v.y - v.x, v.x),
                                        out + tid + k * stride);
        }
        i = tid + 4 * stride;
    }

    // ---- Main streaming loop (batches 2..4 for B = 4M) ----
    for (; i + 3 * stride < n; i += 4 * stride) {
        f32x4 d0 = __builtin_nontemporal_load(data + i);
        f32x4 d1 = __builtin_nontemporal_load(data + i + stride);
        f32x4 d2 = __builtin_nontemporal_load(data + i + 2 * stride);
        f32x4 d3 = __builtin_nontemporal_load(data + i + 3 * stride);

        float r[4];
        f32x4 dd[4] = {d0, d1, d2, d3};
        #pragma unroll
        for (int k = 0; k < 4; ++k) {
            int   idx;
            float fr;
            prep_sample(dd[k], w0, w1, w2, w3, cb, &idx, &fr);
            float2 v = lutl[idx];                 // LDS ds_read_b64
            r[k] = fmaf(fr, v.y - v.x, v.x);
        }

        __builtin_nontemporal_store(r[0], out + i);
        __builtin_nontemporal_store(r[1], out + i + stride);
        __builtin_nontemporal_store(r[2], out + i + 2 * stride);
        __builtin_nontemporal_store(r[3], out + i + 3 * stride);
    }
    // Tail (empty for B = 4M with this grid, kept for robustness).
    for (; i < n; i += stride) {
        f32x4 d = __builtin_nontemporal_load(data + i);
        int   idx;
        float fr;
        prep_sample(d, w0, w1, w2, w3, cb, &idx, &fr);
        float2 v = lutl[idx];
        __builtin_nontemporal_store(fmaf(fr, v.y - v.x, v.x), out + i);
    }
}

extern "C" void kernel_launch(void* const* d_in, const int* in_sizes, int n_in,
                              void* d_out, int out_size, void* d_ws, size_t ws_size,
                              hipStream_t stream) {
    const float* data   = (const float*)d_in[0];
    const float* conv_w = (const float*)d_in[1];
    const float* conv_b = (const float*)d_in[2];
    const float* W_fm = (const float*)d_in[3];  const float* b_fm = (const float*)d_in[4];
    const float* W_c1 = (const float*)d_in[5];  const float* b_c1 = (const float*)d_in[6];
    const float* W_p1 = (const float*)d_in[7];  const float* b_p1 = (const float*)d_in[8];
    const float* W_c2 = (const float*)d_in[9];  const float* b_c2 = (const float*)d_in[10];
    const float* W_p2 = (const float*)d_in[11]; const float* b_p2 = (const float*)d_in[12];
    const float* W_c3 = (const float*)d_in[13]; const float* b_c3 = (const float*)d_in[14];
    const float* W_h  = (const float*)d_in[15]; const float* b_h  = (const float*)d_in[16];
    float* out = (float*)d_out;
    const int B = in_sizes[0] / 4;  // samples; data is B x (1,2,2) = B float4s

    // 256 blocks x 1024 threads: one persistent block per CU, 16 waves/CU.
    qcnn_fused_kernel<<<256, 1024, 0, stream>>>(
        (const f32x4*)data, conv_w, conv_b,
        W_fm, b_fm, W_c1, b_c1, W_p1, b_p1, W_c2, b_c2,
        W_p2, b_p2, W_c3, b_c3, W_h, b_h, out, B);
}